// Round 4
// baseline (460.286 us; speedup 1.0000x reference)
//
#include <hip/hip_runtime.h>
#include <math.h>

#define NCL 10
#define DM 512
#define NH 8
#define DK 64
#define NB 8
#define SL 2048
#define LK 228
#define UF 100
#define KP_PER_B (NH*LK*DK)     // 116736
#define KP_TOT (NB*KP_PER_B)    // 933888
#define NROWS (NB*LK*UF)        // 182400

typedef __bf16 bf16_t;
typedef __attribute__((ext_vector_type(2))) __bf16 bf16x2;
typedef __attribute__((ext_vector_type(4))) __bf16 bf16x4;
typedef __attribute__((ext_vector_type(8))) __bf16 bf16x8;
typedef __attribute__((ext_vector_type(4))) float f32x4;

__device__ __forceinline__ float gelu_f(float x) {
    return 0.5f * x * (1.f + erff(x * 0.70710678118654752f));
}

// ---------------- kernel 0: zero accumulators ----------------
__global__ void k_init(float* __restrict__ acc) {
    if (threadIdx.x < 4) acc[threadIdx.x] = 0.f;
}

// ---------------- kernel 1: max-pool K and V ----------------
__global__ void k_pool(const float* __restrict__ K, const float* __restrict__ V,
                       float* __restrict__ Kp, float* __restrict__ Vp) {
    int idx = blockIdx.x * 256 + threadIdx.x;
    if (idx >= 2 * KP_TOT) return;
    const float* src = (idx < KP_TOT) ? K : V;
    float* dst = (idx < KP_TOT) ? Kp : Vp;
    int e = (idx < KP_TOT) ? idx : idx - KP_TOT;
    int b   = e / KP_PER_B;
    int off = e % KP_PER_B;
    int c  = off / LK;        // channel 0..511
    int pp = off % LK;        // pooled position 0..227
    int p0 = pp * 9 - 4;
    const float* base = src + (size_t)b * 1048576 + (size_t)c * 2048;
    float mx = -3.4e38f;
    #pragma unroll
    for (int j = 0; j < 9; ++j) {
        int p = p0 + j;
        if (p >= 0 && p < 2048) mx = fmaxf(mx, base[p]);
    }
    dst[e] = mx;
}

// ---------------- kernel 2: SPARSE q-MLP + softmax + stats + centers ----
// X[m][c] (100x512 per (b,l) block) is nonzero only at g=m*512+c with
// g%100 >= 100-b: exactly b nonzeros per 100-run, value Sst[rl][s] at
// g = 100*rl + 99-b+s (s=1..b). So hT = X*W1 is computed as a sparse
// scatter of scaled W1 rows: ~131M FMA total instead of 3.7G dense.
// LDS (64528 B, 2 blocks/CU):
//   0     W1L  bf16[512][40]  (40960)
//   40960 SstL bf16[512][7]   ( 7168)  -- aliased by stats after accumulation
//   48128 hT   f32[100][41]   (16400)  (stride 41: layer-2 reads conflict-free)
__global__ __launch_bounds__(256, 2) void k_mlp(
        const float* __restrict__ Kp,
        const float* __restrict__ Wq1, const float* __restrict__ bq1,
        const float* __restrict__ Wq2, const float* __restrict__ bq2,
        float* __restrict__ mu_g, float* __restrict__ centers_g,
        float* __restrict__ acc_g) {
    __shared__ __align__(16) char smem[64528];
    bf16_t* W1L  = (bf16_t*)smem;                 // [512][40]
    bf16_t* SstL = (bf16_t*)(smem + 40960);       // [512][7], slots 1..7 -> idx 0..6
    float*  hT   = (float*)(smem + 48128);        // [100][41]
    float*  stats = (float*)(smem + 40960);       // alias: [0..9]=total, [10..109]=S, [110]=lp

    int tid = threadIdx.x;
    int bl = blockIdx.x;          // 0..1823
    int b = bl / LK;
    int l = bl % LK;

    // stage W1 -> bf16 LDS (flat copy, row-major [c][n]), vectorized
    for (int i = tid; i < 10240; i += 256) {
        float2 w = *(const float2*)&Wq1[i * 2];
        *(bf16x2*)&W1L[i * 2] = (bf16x2){(bf16_t)w.x, (bf16_t)w.y};
    }
    // stage Sst values (source batches 1..7)
    if (b > 0) {
        for (int s = tid; s < 512 * 7; s += 256) {
            int rl = s / 7;
            int bk = s - rl * 7 + 1;
            int rg = l * 512 + rl;
            int hh = rg / 14592;
            int rh = rg % 14592;
            int lp_ = rh >> 6;
            int dd = rh & 63;
            SstL[s] = (bf16_t)Kp[((bk * NH + hh) * LK + lp_) * DK + dd];
        }
    }
    for (int i = tid; i < 4100; i += 256) hT[i] = 0.f;
    __syncthreads();

    // ---- sparse accumulation: 24 lane-groups of 10, 22 runs each ----
    if (b > 0) {
        int lane = tid & 63;
        int wid = tid >> 6;
        int grp = lane / 10;        // 0..6 (grp 6 = lanes 60..63: inactive)
        int n4 = lane - grp * 10;   // 0..9 -> hidden cols n4*4..n4*4+3
        if (grp < 6) {
            int gi = wid * 6 + grp;     // 0..23
            int rl0 = gi * 22;
            int rlend = min(rl0 + 22, 512);
            float4 acc = make_float4(0.f, 0.f, 0.f, 0.f);
            int mcur = -1;
            for (int rl = rl0; rl < rlend; ++rl) {
                int gb = 100 * rl + 99 - b;
                #pragma unroll
                for (int s = 1; s <= 7; ++s) {
                    if (s <= b) {
                        int g = gb + s;
                        int m = g >> 9;
                        int c = g & 511;
                        if (m != mcur) {
                            if (mcur >= 0) {
                                float* hrow = &hT[mcur * 41 + n4 * 4];
                                atomicAdd(hrow + 0, acc.x);
                                atomicAdd(hrow + 1, acc.y);
                                atomicAdd(hrow + 2, acc.z);
                                atomicAdd(hrow + 3, acc.w);
                                acc = make_float4(0.f, 0.f, 0.f, 0.f);
                            }
                            mcur = m;
                        }
                        float v = (float)SstL[rl * 7 + s - 1];
                        bf16x4 wv = *(const bf16x4*)&W1L[c * 40 + n4 * 4];
                        acc.x = fmaf(v, (float)wv[0], acc.x);
                        acc.y = fmaf(v, (float)wv[1], acc.y);
                        acc.z = fmaf(v, (float)wv[2], acc.z);
                        acc.w = fmaf(v, (float)wv[3], acc.w);
                    }
                }
            }
            if (mcur >= 0) {
                float* hrow = &hT[mcur * 41 + n4 * 4];
                atomicAdd(hrow + 0, acc.x);
                atomicAdd(hrow + 1, acc.y);
                atomicAdd(hrow + 2, acc.z);
                atomicAdd(hrow + 3, acc.w);
            }
        }
    }
    __syncthreads();

    // ---- gelu(+bias) in place, all threads; zero stats (aliases dead SstL) ----
    if (tid < 111) stats[tid] = 0.f;
    for (int i = tid; i < 4000; i += 256) {
        int row = i / 40;
        int j = i - row * 40;
        hT[row * 41 + j] = gelu_f(hT[row * 41 + j] + bq1[j]);
    }
    __syncthreads();

    float* total_l = stats;
    float* S_l = stats + 10;
    float* lp_acc = stats + 110;

    if (tid < 100) {
        int row = tid;
        float out[10];
        #pragma unroll
        for (int c = 0; c < 10; ++c) out[c] = bq2[c];
        #pragma unroll
        for (int j = 0; j < 40; ++j) {
            float gj = hT[row * 41 + j];
            #pragma unroll
            for (int c = 0; c < 10; ++c)
                out[c] = fmaf(gj, Wq2[j * 10 + c], out[c]);
        }
        float m = out[0]; int am = 0;
        #pragma unroll
        for (int c = 1; c < 10; ++c)
            if (out[c] > m) { m = out[c]; am = c; }
        float e[10], s = 0.f;
        #pragma unroll
        for (int c = 0; c < 10; ++c) { e[c] = expf(out[c] - m); s += e[c]; }
        float inv = 1.f / s;
        float cq[10], s1 = 0.f;
        #pragma unroll
        for (int c = 0; c < 10; ++c) { cq[c] = e[c] * inv; s1 += cq[c]; }
        float mean = s1 * 0.1f;
        float var = 0.f;
        #pragma unroll
        for (int c = 0; c < 10; ++c) { float d = cq[c] - mean; var += d * d; }
        float sd = sqrtf(var / 9.f);
        float sp = log1pf(expf(sd));             // softplus(std)
        float lp = -logf(sp) - 0.91893853320467274f;  // ((x-mu)/sigma)^2 ~ 1e-16
        mu_g[bl * 100 + row] = mean;
        atomicAdd(lp_acc, lp);
        #pragma unroll
        for (int c = 0; c < 10; ++c) {
            atomicAdd(&total_l[c], cq[c]);
            atomicAdd(&S_l[am * 10 + c], cq[c]);
        }
    }
    __syncthreads();
    if (tid == 0) atomicAdd(&acc_g[0], lp_acc[0]);
    if (tid < 100) {
        centers_g[bl * 100 + tid] = (total_l[tid % 10] - S_l[tid]) * 0.01f;
    }
}

// ---------------- kernel 3: cross-entropy over l axis ----------------
__global__ void k_ce(const float* __restrict__ mu_g, float* __restrict__ acc_g) {
    int bid = blockIdx.x;     // 800 = (b,u)
    int b = bid / 100;
    int u = bid % 100;
    int lane = threadIdx.x;   // 64
    float v[4];
    #pragma unroll
    for (int t = 0; t < 4; ++t) {
        int l = lane + t * 64;
        v[t] = (l < LK) ? mu_g[(b * LK + l) * 100 + u] : -3.4e38f;
    }
    float m = fmaxf(fmaxf(v[0], v[1]), fmaxf(v[2], v[3]));
    for (int o = 32; o > 0; o >>= 1) m = fmaxf(m, __shfl_xor(m, o, 64));
    float se = 0.f;
    #pragma unroll
    for (int t = 0; t < 4; ++t) {
        int l = lane + t * 64;
        if (l < LK) se += expf(v[t] - m);
    }
    for (int o = 32; o > 0; o >>= 1) se += __shfl_xor(se, o, 64);
    float lse = m + logf(se);
    float dot = 0.f;
    #pragma unroll
    for (int t = 0; t < 4; ++t) {
        int l = lane + t * 64;
        if (l < LK) dot += v[t] * (v[t] - lse);
    }
    for (int o = 32; o > 0; o >>= 1) dot += __shfl_xor(dot, o, 64);
    if (lane == 0) atomicAdd(&acc_g[1], -dot * (1.f / 800.f));
}

// ---------------- kernel 4: fused proj_back(gelu) + reshape-sum over clusters ----------------
__global__ void k_ccs(const float* __restrict__ centers_g,
                      const float* __restrict__ Wp, const float* __restrict__ bp,
                      float* __restrict__ ccs) {
    int tid = blockIdx.x * 256 + threadIdx.x;
    if (tid >= KP_TOT) return;
    int k2d2 = tid % (LK * DK);
    int bh = tid / (LK * DK);
    float s = 0.f;
    #pragma unroll
    for (int i2 = 0; i2 < 10; ++i2) {
        int t2 = bh * 145920 + i2 * 14592 + k2d2;   // flat index into cc [10,8,228,512]
        int i = t2 / 933888;
        int r1 = t2 % 933888;
        int bs = r1 / 116736;
        int r2 = r1 % 116736;
        int ls = r2 / 512;
        int mm = r2 % 512;
        const float* cen = centers_g + (bs * LK + ls) * 100 + i * 10;
        float val = bp[mm];
        #pragma unroll
        for (int c = 0; c < 10; ++c)
            val = fmaf(cen[c], Wp[c * 512 + mm], val);
        s += gelu_f(val);
    }
    ccs[tid] = s;
}

// ---------------- kernel 5: MFMA flash attention (228 keys, chunks of 64) ----------------
#define QT 128
__global__ __launch_bounds__(256, 3) void k_attn(
        const float* __restrict__ Q, const float* __restrict__ ccs,
        const float* __restrict__ Vp, float* __restrict__ outp) {
    __shared__ __align__(16) char smem[36864];
    bf16_t* Kl = (bf16_t*)(smem);
    bf16_t* Vt = (bf16_t*)(smem + 9216);
    bf16_t* Pl = (bf16_t*)(smem + 18432);

    int tid = threadIdx.x;
    int wid = tid >> 6;
    int lane = tid & 63;
    int ln = lane & 15;
    int qd = lane >> 4;
    int bid = blockIdx.x;        // 1024
    int bh = bid >> 4;           // b*8+h
    int qt = bid & 15;
    int qbase = qt * QT;

    const float* Qbh = Q + (size_t)bh * SL * DK;
    const float* Kbh = ccs + (size_t)bh * LK * DK;
    const float* Vbh = Vp + (size_t)bh * LK * DK;

    for (int s = tid; s < QT * 32; s += 256) {
        int r = s >> 5;
        int c2 = s & 31;
        float2 v = *(const float2*)&Qbh[(size_t)(qbase + r) * DK + c2 * 2];
        *(bf16x2*)&Pl[r * 72 + c2 * 2] = (bf16x2){(bf16_t)v.x, (bf16_t)v.y};
    }
    __syncthreads();
    bf16x8 qf[2][2];
    #pragma unroll
    for (int mt = 0; mt < 2; ++mt)
        #pragma unroll
        for (int ks = 0; ks < 2; ++ks)
            qf[mt][ks] = *(const bf16x8*)&Pl[(wid * 32 + mt * 16 + ln) * 72 + ks * 32 + qd * 8];

    f32x4 acc_o[2][4];
    float mrow[2][4], lrow[2][4];
    #pragma unroll
    for (int mt = 0; mt < 2; ++mt)
        #pragma unroll
        for (int t = 0; t < 4; ++t) {
            acc_o[mt][t] = (f32x4)(0.f);
            mrow[mt][t] = -3.0e38f;
            lrow[mt][t] = 0.f;
        }

    for (int ch = 0; ch < 4; ++ch) {
        int k0 = ch * 64;
        __syncthreads();
        for (int s = tid; s < 64 * 32; s += 256) {
            int kk = s >> 5;
            int c2 = s & 31;
            int key = k0 + kk;
            float2 v = (key < LK) ? *(const float2*)&Kbh[(size_t)key * DK + c2 * 2]
                                  : make_float2(0.f, 0.f);
            *(bf16x2*)&Kl[kk * 72 + c2 * 2] = (bf16x2){(bf16_t)v.x, (bf16_t)v.y};
        }
        for (int s = tid; s < 64 * 16; s += 256) {
            int kk = s >> 4;
            int c4 = s & 15;
            int key = k0 + kk;
            float4 v = (key < LK) ? *(const float4*)&Vbh[(size_t)key * DK + c4 * 4]
                                  : make_float4(0.f, 0.f, 0.f, 0.f);
            Vt[(c4 * 4 + 0) * 72 + kk] = (bf16_t)v.x;
            Vt[(c4 * 4 + 1) * 72 + kk] = (bf16_t)v.y;
            Vt[(c4 * 4 + 2) * 72 + kk] = (bf16_t)v.z;
            Vt[(c4 * 4 + 3) * 72 + kk] = (bf16_t)v.w;
        }
        __syncthreads();

        f32x4 accs[2][4];
        #pragma unroll
        for (int mt = 0; mt < 2; ++mt)
            #pragma unroll
            for (int nt = 0; nt < 4; ++nt) accs[mt][nt] = (f32x4)(0.f);
        #pragma unroll
        for (int ks = 0; ks < 2; ++ks) {
            #pragma unroll
            for (int nt = 0; nt < 4; ++nt) {
                bf16x8 bf = *(const bf16x8*)&Kl[(nt * 16 + ln) * 72 + ks * 32 + qd * 8];
                #pragma unroll
                for (int mt = 0; mt < 2; ++mt)
                    accs[mt][nt] = __builtin_amdgcn_mfma_f32_16x16x32_bf16(qf[mt][ks], bf, accs[mt][nt], 0, 0, 0);
            }
        }

        #pragma unroll
        for (int mt = 0; mt < 2; ++mt) {
            #pragma unroll
            for (int r = 0; r < 4; ++r) {
                float sv[4];
                #pragma unroll
                for (int nt = 0; nt < 4; ++nt) {
                    float s = accs[mt][nt][r] * 0.125f;
                    int key = k0 + nt * 16 + ln;
                    sv[nt] = (key < LK) ? s : -3.0e38f;
                }
                float rmax = fmaxf(fmaxf(sv[0], sv[1]), fmaxf(sv[2], sv[3]));
                #pragma unroll
                for (int o = 1; o < 16; o <<= 1)
                    rmax = fmaxf(rmax, __shfl_xor(rmax, o, 64));
                float mold = mrow[mt][r];
                float mnew = fmaxf(mold, rmax);
                float alpha = __expf(mold - mnew);
                float p[4], psum = 0.f;
                #pragma unroll
                for (int nt = 0; nt < 4; ++nt) {
                    p[nt] = __expf(sv[nt] - mnew);
                    psum += p[nt];
                }
                #pragma unroll
                for (int o = 1; o < 16; o <<= 1)
                    psum += __shfl_xor(psum, o, 64);
                lrow[mt][r] = lrow[mt][r] * alpha + psum;
                mrow[mt][r] = mnew;
                #pragma unroll
                for (int ntv = 0; ntv < 4; ++ntv)
                    acc_o[mt][ntv][r] *= alpha;
                int prow = (wid * 32 + mt * 16 + qd * 4 + r) * 72;
                #pragma unroll
                for (int nt = 0; nt < 4; ++nt)
                    Pl[prow + nt * 16 + ln] = (bf16_t)p[nt];
            }
        }

        #pragma unroll
        for (int ks = 0; ks < 2; ++ks) {
            bf16x8 pa[2];
            #pragma unroll
            for (int mt = 0; mt < 2; ++mt)
                pa[mt] = *(const bf16x8*)&Pl[(wid * 32 + mt * 16 + ln) * 72 + ks * 32 + qd * 8];
            #pragma unroll
            for (int ntv = 0; ntv < 4; ++ntv) {
                bf16x8 vb = *(const bf16x8*)&Vt[(ntv * 16 + ln) * 72 + ks * 32 + qd * 8];
                #pragma unroll
                for (int mt = 0; mt < 2; ++mt)
                    acc_o[mt][ntv] = __builtin_amdgcn_mfma_f32_16x16x32_bf16(pa[mt], vb, acc_o[mt][ntv], 0, 0, 0);
            }
        }
    }

    #pragma unroll
    for (int mt = 0; mt < 2; ++mt) {
        #pragma unroll
        for (int r = 0; r < 4; ++r) {
            float inv = 1.f / lrow[mt][r];
            int q_idx = qbase + wid * 32 + mt * 16 + qd * 4 + r;
            float* orow = outp + ((size_t)bh * SL + q_idx) * DK;
            #pragma unroll
            for (int ntv = 0; ntv < 4; ++ntv)
                orow[ntv * 16 + ln] = acc_o[mt][ntv][r] * inv;
        }
    }
}

// ---------------- kernel 6: final loss ----------------
__global__ void k_final(const float* __restrict__ acc_g, float* __restrict__ outp) {
    outp[8388608] = -(acc_g[0] * (1.f / (float)NROWS)) + acc_g[1];
}

extern "C" void kernel_launch(void* const* d_in, const int* in_sizes, int n_in,
                              void* d_out, int out_size, void* d_ws, size_t ws_size,
                              hipStream_t stream) {
    const float* Q   = (const float*)d_in[0];
    const float* K   = (const float*)d_in[1];
    const float* V   = (const float*)d_in[2];
    const float* Wq1 = (const float*)d_in[7];
    const float* bq1 = (const float*)d_in[8];
    const float* Wq2 = (const float*)d_in[9];
    const float* bq2 = (const float*)d_in[10];
    const float* Wp  = (const float*)d_in[11];
    const float* bp  = (const float*)d_in[12];
    float* out = (float*)d_out;

    float* ws      = (float*)d_ws;
    float* Kp      = ws;                 // 933888
    float* Vp      = ws + 933888;        // 933888
    float* mu      = ws + 1867776;       // 182400
    float* centers = ws + 2050176;       // 182400
    float* ccs     = ws + 2232576;       // 933888
    float* acc     = ws + 3166464;       // 4

    k_init<<<1, 64, 0, stream>>>(acc);
    k_pool<<<(2 * KP_TOT + 255) / 256, 256, 0, stream>>>(K, V, Kp, Vp);
    k_mlp<<<NB * LK, 256, 0, stream>>>(Kp, Wq1, bq1, Wq2, bq2, mu, centers, acc);
    k_ce<<<NB * 100, 64, 0, stream>>>(mu, acc);
    k_ccs<<<(KP_TOT + 255) / 256, 256, 0, stream>>>(centers, Wp, bp, ccs);
    k_attn<<<NB * NH * (SL / QT), 256, 0, stream>>>(Q, ccs, Vp, out);
    k_final<<<1, 1, 0, stream>>>(acc, out);
}

// Round 5
// 447.947 us; speedup vs baseline: 1.0275x; 1.0275x over previous
//
#include <hip/hip_runtime.h>
#include <math.h>

#define NCL 10
#define DM 512
#define NH 8
#define DK 64
#define NB 8
#define SL 2048
#define LK 228
#define UF 100
#define KP_PER_B (NH*LK*DK)     // 116736
#define KP_TOT (NB*KP_PER_B)    // 933888
#define NROWS (NB*LK*UF)        // 182400

typedef __bf16 bf16_t;
typedef __attribute__((ext_vector_type(2))) __bf16 bf16x2;
typedef __attribute__((ext_vector_type(8))) __bf16 bf16x8;
typedef __attribute__((ext_vector_type(4))) float f32x4;

__device__ __forceinline__ float gelu_f(float x) {
    return 0.5f * x * (1.f + erff(x * 0.70710678118654752f));
}

// ---------------- kernel 0: zero accumulators ----------------
__global__ void k_init(float* __restrict__ acc) {
    if (threadIdx.x < 4) acc[threadIdx.x] = 0.f;
}

// ---------------- kernel 0b: W1^T -> bf16 global [48][512] (rows 40..47 zero) ----
__global__ void k_prep(const float* __restrict__ Wq1, bf16_t* __restrict__ W1T) {
    int i = blockIdx.x * 256 + threadIdx.x;
    if (i >= 48 * 512) return;
    int n = i >> 9, f = i & 511;
    W1T[i] = (n < 40) ? (bf16_t)Wq1[f * 40 + n] : (bf16_t)0.f;
}

// ---------------- kernel 1: max-pool K and V ----------------
__global__ void k_pool(const float* __restrict__ K, const float* __restrict__ V,
                       float* __restrict__ Kp, float* __restrict__ Vp) {
    int idx = blockIdx.x * 256 + threadIdx.x;
    if (idx >= 2 * KP_TOT) return;
    const float* src = (idx < KP_TOT) ? K : V;
    float* dst = (idx < KP_TOT) ? Kp : Vp;
    int e = (idx < KP_TOT) ? idx : idx - KP_TOT;
    int b   = e / KP_PER_B;
    int off = e % KP_PER_B;
    int c  = off / LK;        // channel 0..511
    int pp = off % LK;        // pooled position 0..227
    int p0 = pp * 9 - 4;
    const float* base = src + (size_t)b * 1048576 + (size_t)c * 2048;
    float mx = -3.4e38f;
    #pragma unroll
    for (int j = 0; j < 9; ++j) {
        int p = p0 + j;
        if (p >= 0 && p < 2048) mx = fmaxf(mx, base[p]);
    }
    dst[e] = mx;
}

// ---------------- kernel 2: MFMA q-MLP with incremental sparse staging ----------
// X (100x512 per (b,l)) has b nonzeros per 100-run: g = 100*rl + 99-b+s (s=1..b),
// value Kp[s*116736 + l*512 + rl], at row m=g>>9, col f=g&511. Chunked 64-wide
// k-GEMM (16x16x32 MFMA); per chunk each thread zeroes its prev-chunk writes and
// scatters its new ones (positions never collide: band shift 64-36 > band width 7).
// W1^T streamed from global bf16 (L1/L2 resident). LDS 25 KB -> ~5 blocks/CU.
// LDS: XA bf16[112][72] (16128) | 16384 Sst2 bf16[8][512] (rows 1..7) |
//      hT f32[100][41] aliases XA | stats 111 f32 @ 24576
__global__ __launch_bounds__(256, 4) void k_mlp(
        const float* __restrict__ Kp, const bf16_t* __restrict__ W1T,
        const float* __restrict__ bq1,
        const float* __restrict__ Wq2, const float* __restrict__ bq2,
        float* __restrict__ mu_g, float* __restrict__ centers_g,
        float* __restrict__ acc_g) {
    __shared__ __align__(16) char smem[25024];
    bf16_t* XA    = (bf16_t*)smem;               // [112][72]
    bf16_t* Sst2  = (bf16_t*)(smem + 16384);     // [8][512], rows 1..7 used
    float*  hT    = (float*)smem;                // [100][41] alias of XA
    float*  stats = (float*)(smem + 24576);      // [0..9]=total [10..109]=S [110]=lp

    int tid = threadIdx.x;
    int bl = blockIdx.x;          // 0..1823
    int b = bl / LK;
    int l = bl % LK;
    int wid = tid >> 6;
    int lane = tid & 63;
    int ln = lane & 15;
    int qd = lane >> 4;

    f32x4 acc[6];
    #pragma unroll
    for (int t = 0; t < 6; ++t) acc[t] = (f32x4)(0.f);

    if (b > 0) {
        // zero XA (112*72 bf16 = 1008 int4)
        for (int i = tid; i < 1008; i += 256)
            ((int4*)XA)[i] = make_int4(0, 0, 0, 0);
        // stage Sst2 rows 1..b: coalesced contiguous copy from Kp
        for (int s = tid; s < 512 * b; s += 256) {
            int bk = (s >> 9) + 1;
            int rl = s & 511;
            Sst2[(bk << 9) + rl] = (bf16_t)Kp[bk * KP_PER_B + l * 512 + rl];
        }
        __syncthreads();

        for (int ch = 0; ch < 8; ++ch) {
            int kc = ch << 6;
            int chp = ch - 1;
            // incremental scatter: zero prev-chunk entries, write cur-chunk entries
            #pragma unroll
            for (int rr = 0; rr < 2; ++rr) {
                int rl = tid + (rr << 8);
                int g0 = 100 * rl + 99 - b;
                int fA = (g0 + 1) & 511, fB = (g0 + b) & 511;
                int cA = fA >> 6, cB = fB >> 6;
                if (cA == ch || cB == ch || cA == chp || cB == chp) {
                    for (int s = 1; s <= b; ++s) {
                        int g = g0 + s;
                        int f = g & 511;
                        int fc = f >> 6;
                        int addr = (g >> 9) * 72 + (f & 63);
                        if (fc == chp) XA[addr] = (bf16_t)0.f;
                        else if (fc == ch) XA[addr] = Sst2[(s << 9) + rl];
                    }
                }
            }
            // preload B-frags for this chunk (global, L1/L2-resident)
            bf16x8 bb[3][2];
            #pragma unroll
            for (int nt = 0; nt < 3; ++nt)
                #pragma unroll
                for (int ks = 0; ks < 2; ++ks)
                    bb[nt][ks] = *(const bf16x8*)&W1T[(nt * 16 + ln) * 512 + kc + ks * 32 + qd * 8];
            __syncthreads();
            #pragma unroll
            for (int t = 0; t < 6; ++t) {
                int tile = wid + (t << 2);
                if (tile < 21) {
                    int mt = tile / 3;
                    int nt = tile - mt * 3;
                    #pragma unroll
                    for (int ks = 0; ks < 2; ++ks) {
                        bf16x8 a = *(const bf16x8*)&XA[(mt * 16 + ln) * 72 + ks * 32 + qd * 8];
                        acc[t] = __builtin_amdgcn_mfma_f32_16x16x32_bf16(a, bb[nt][ks], acc[t], 0, 0, 0);
                    }
                }
            }
            __syncthreads();
        }
    }

    // write D (no bias yet) into hT [100][41] (aliases XA; all XA reads done)
    #pragma unroll
    for (int t = 0; t < 6; ++t) {
        int tile = wid + (t << 2);
        if (tile < 21) {
            int mt = tile / 3;
            int nt = tile - mt * 3;
            int n = nt * 16 + ln;
            if (n < 40) {
                #pragma unroll
                for (int r = 0; r < 4; ++r) {
                    int m = mt * 16 + qd * 4 + r;
                    if (m < 100) hT[m * 41 + n] = acc[t][r];
                }
            }
        }
    }
    if (tid < 111) stats[tid] = 0.f;
    __syncthreads();

    // gelu(+bias) in place, distributed over all threads
    for (int i = tid; i < 4000; i += 256) {
        int row = i / 40;
        int j = i - row * 40;
        hT[row * 41 + j] = gelu_f(hT[row * 41 + j] + bq1[j]);
    }
    __syncthreads();

    float* total_l = stats;
    float* S_l = stats + 10;
    float* lp_acc = stats + 110;

    if (tid < 100) {
        int row = tid;
        float out[10];
        #pragma unroll
        for (int c = 0; c < 10; ++c) out[c] = bq2[c];
        #pragma unroll
        for (int j = 0; j < 40; ++j) {
            float gj = hT[row * 41 + j];
            #pragma unroll
            for (int c = 0; c < 10; ++c)
                out[c] = fmaf(gj, Wq2[j * 10 + c], out[c]);
        }
        float m = out[0]; int am = 0;
        #pragma unroll
        for (int c = 1; c < 10; ++c)
            if (out[c] > m) { m = out[c]; am = c; }
        float e[10], s = 0.f;
        #pragma unroll
        for (int c = 0; c < 10; ++c) { e[c] = expf(out[c] - m); s += e[c]; }
        float inv = 1.f / s;
        float cq[10], s1 = 0.f;
        #pragma unroll
        for (int c = 0; c < 10; ++c) { cq[c] = e[c] * inv; s1 += cq[c]; }
        float mean = s1 * 0.1f;
        float var = 0.f;
        #pragma unroll
        for (int c = 0; c < 10; ++c) { float d = cq[c] - mean; var += d * d; }
        float sd = sqrtf(var / 9.f);
        float sp = log1pf(expf(sd));             // softplus(std)
        float lp = -logf(sp) - 0.91893853320467274f;  // ((x-mu)/sigma)^2 ~ 1e-16
        mu_g[bl * 100 + row] = mean;
        atomicAdd(lp_acc, lp);
        #pragma unroll
        for (int c = 0; c < 10; ++c) {
            atomicAdd(&total_l[c], cq[c]);
            atomicAdd(&S_l[am * 10 + c], cq[c]);
        }
    }
    __syncthreads();
    if (tid == 0) atomicAdd(&acc_g[0], lp_acc[0]);
    if (tid < 100) {
        centers_g[bl * 100 + tid] = (total_l[tid % 10] - S_l[tid]) * 0.01f;
    }
}

// ---------------- kernel 3: cross-entropy over l axis ----------------
__global__ void k_ce(const float* __restrict__ mu_g, float* __restrict__ acc_g) {
    int bid = blockIdx.x;     // 800 = (b,u)
    int b = bid / 100;
    int u = bid % 100;
    int lane = threadIdx.x;   // 64
    float v[4];
    #pragma unroll
    for (int t = 0; t < 4; ++t) {
        int l = lane + t * 64;
        v[t] = (l < LK) ? mu_g[(b * LK + l) * 100 + u] : -3.4e38f;
    }
    float m = fmaxf(fmaxf(v[0], v[1]), fmaxf(v[2], v[3]));
    for (int o = 32; o > 0; o >>= 1) m = fmaxf(m, __shfl_xor(m, o, 64));
    float se = 0.f;
    #pragma unroll
    for (int t = 0; t < 4; ++t) {
        int l = lane + t * 64;
        if (l < LK) se += expf(v[t] - m);
    }
    for (int o = 32; o > 0; o >>= 1) se += __shfl_xor(se, o, 64);
    float lse = m + logf(se);
    float dot = 0.f;
    #pragma unroll
    for (int t = 0; t < 4; ++t) {
        int l = lane + t * 64;
        if (l < LK) dot += v[t] * (v[t] - lse);
    }
    for (int o = 32; o > 0; o >>= 1) dot += __shfl_xor(dot, o, 64);
    if (lane == 0) atomicAdd(&acc_g[1], -dot * (1.f / 800.f));
}

// ---------------- kernel 4: fused proj_back(gelu) + reshape-sum over clusters ----------------
__global__ void k_ccs(const float* __restrict__ centers_g,
                      const float* __restrict__ Wp, const float* __restrict__ bp,
                      float* __restrict__ ccs) {
    int tid = blockIdx.x * 256 + threadIdx.x;
    if (tid >= KP_TOT) return;
    int k2d2 = tid % (LK * DK);
    int bh = tid / (LK * DK);
    float s = 0.f;
    #pragma unroll
    for (int i2 = 0; i2 < 10; ++i2) {
        int t2 = bh * 145920 + i2 * 14592 + k2d2;   // flat index into cc [10,8,228,512]
        int i = t2 / 933888;
        int r1 = t2 % 933888;
        int bs = r1 / 116736;
        int r2 = r1 % 116736;
        int ls = r2 / 512;
        int mm = r2 % 512;
        const float* cen = centers_g + (bs * LK + ls) * 100 + i * 10;
        float val = bp[mm];
        #pragma unroll
        for (int c = 0; c < 10; ++c)
            val = fmaf(cen[c], Wp[c * 512 + mm], val);
        s += gelu_f(val);
    }
    ccs[tid] = s;
}

// ---------------- kernel 5: MFMA flash attention (228 keys, chunks of 64) ----------------
#define QT 128
__global__ __launch_bounds__(256, 3) void k_attn(
        const float* __restrict__ Q, const float* __restrict__ ccs,
        const float* __restrict__ Vp, float* __restrict__ outp) {
    __shared__ __align__(16) char smem[36864];
    bf16_t* Kl = (bf16_t*)(smem);
    bf16_t* Vt = (bf16_t*)(smem + 9216);
    bf16_t* Pl = (bf16_t*)(smem + 18432);

    int tid = threadIdx.x;
    int wid = tid >> 6;
    int lane = tid & 63;
    int ln = lane & 15;
    int qd = lane >> 4;
    int bid = blockIdx.x;        // 1024
    int bh = bid >> 4;           // b*8+h
    int qt = bid & 15;
    int qbase = qt * QT;

    const float* Qbh = Q + (size_t)bh * SL * DK;
    const float* Kbh = ccs + (size_t)bh * LK * DK;
    const float* Vbh = Vp + (size_t)bh * LK * DK;

    for (int s = tid; s < QT * 32; s += 256) {
        int r = s >> 5;
        int c2 = s & 31;
        float2 v = *(const float2*)&Qbh[(size_t)(qbase + r) * DK + c2 * 2];
        *(bf16x2*)&Pl[r * 72 + c2 * 2] = (bf16x2){(bf16_t)v.x, (bf16_t)v.y};
    }
    __syncthreads();
    bf16x8 qf[2][2];
    #pragma unroll
    for (int mt = 0; mt < 2; ++mt)
        #pragma unroll
        for (int ks = 0; ks < 2; ++ks)
            qf[mt][ks] = *(const bf16x8*)&Pl[(wid * 32 + mt * 16 + ln) * 72 + ks * 32 + qd * 8];

    f32x4 acc_o[2][4];
    float mrow[2][4], lrow[2][4];
    #pragma unroll
    for (int mt = 0; mt < 2; ++mt)
        #pragma unroll
        for (int t = 0; t < 4; ++t) {
            acc_o[mt][t] = (f32x4)(0.f);
            mrow[mt][t] = -3.0e38f;
            lrow[mt][t] = 0.f;
        }

    for (int ch = 0; ch < 4; ++ch) {
        int k0 = ch * 64;
        __syncthreads();
        for (int s = tid; s < 64 * 32; s += 256) {
            int kk = s >> 5;
            int c2 = s & 31;
            int key = k0 + kk;
            float2 v = (key < LK) ? *(const float2*)&Kbh[(size_t)key * DK + c2 * 2]
                                  : make_float2(0.f, 0.f);
            *(bf16x2*)&Kl[kk * 72 + c2 * 2] = (bf16x2){(bf16_t)v.x, (bf16_t)v.y};
        }
        for (int s = tid; s < 64 * 16; s += 256) {
            int kk = s >> 4;
            int c4 = s & 15;
            int key = k0 + kk;
            float4 v = (key < LK) ? *(const float4*)&Vbh[(size_t)key * DK + c4 * 4]
                                  : make_float4(0.f, 0.f, 0.f, 0.f);
            Vt[(c4 * 4 + 0) * 72 + kk] = (bf16_t)v.x;
            Vt[(c4 * 4 + 1) * 72 + kk] = (bf16_t)v.y;
            Vt[(c4 * 4 + 2) * 72 + kk] = (bf16_t)v.z;
            Vt[(c4 * 4 + 3) * 72 + kk] = (bf16_t)v.w;
        }
        __syncthreads();

        f32x4 accs[2][4];
        #pragma unroll
        for (int mt = 0; mt < 2; ++mt)
            #pragma unroll
            for (int nt = 0; nt < 4; ++nt) accs[mt][nt] = (f32x4)(0.f);
        #pragma unroll
        for (int ks = 0; ks < 2; ++ks) {
            #pragma unroll
            for (int nt = 0; nt < 4; ++nt) {
                bf16x8 bf = *(const bf16x8*)&Kl[(nt * 16 + ln) * 72 + ks * 32 + qd * 8];
                #pragma unroll
                for (int mt = 0; mt < 2; ++mt)
                    accs[mt][nt] = __builtin_amdgcn_mfma_f32_16x16x32_bf16(qf[mt][ks], bf, accs[mt][nt], 0, 0, 0);
            }
        }

        #pragma unroll
        for (int mt = 0; mt < 2; ++mt) {
            #pragma unroll
            for (int r = 0; r < 4; ++r) {
                float sv[4];
                #pragma unroll
                for (int nt = 0; nt < 4; ++nt) {
                    float s = accs[mt][nt][r] * 0.125f;
                    int key = k0 + nt * 16 + ln;
                    sv[nt] = (key < LK) ? s : -3.0e38f;
                }
                float rmax = fmaxf(fmaxf(sv[0], sv[1]), fmaxf(sv[2], sv[3]));
                #pragma unroll
                for (int o = 1; o < 16; o <<= 1)
                    rmax = fmaxf(rmax, __shfl_xor(rmax, o, 64));
                float mold = mrow[mt][r];
                float mnew = fmaxf(mold, rmax);
                float alpha = __expf(mold - mnew);
                float p[4], psum = 0.f;
                #pragma unroll
                for (int nt = 0; nt < 4; ++nt) {
                    p[nt] = __expf(sv[nt] - mnew);
                    psum += p[nt];
                }
                #pragma unroll
                for (int o = 1; o < 16; o <<= 1)
                    psum += __shfl_xor(psum, o, 64);
                lrow[mt][r] = lrow[mt][r] * alpha + psum;
                mrow[mt][r] = mnew;
                #pragma unroll
                for (int ntv = 0; ntv < 4; ++ntv)
                    acc_o[mt][ntv][r] *= alpha;
                int prow = (wid * 32 + mt * 16 + qd * 4 + r) * 72;
                #pragma unroll
                for (int nt = 0; nt < 4; ++nt)
                    Pl[prow + nt * 16 + ln] = (bf16_t)p[nt];
            }
        }

        #pragma unroll
        for (int ks = 0; ks < 2; ++ks) {
            bf16x8 pa[2];
            #pragma unroll
            for (int mt = 0; mt < 2; ++mt)
                pa[mt] = *(const bf16x8*)&Pl[(wid * 32 + mt * 16 + ln) * 72 + ks * 32 + qd * 8];
            #pragma unroll
            for (int ntv = 0; ntv < 4; ++ntv) {
                bf16x8 vb = *(const bf16x8*)&Vt[(ntv * 16 + ln) * 72 + ks * 32 + qd * 8];
                #pragma unroll
                for (int mt = 0; mt < 2; ++mt)
                    acc_o[mt][ntv] = __builtin_amdgcn_mfma_f32_16x16x32_bf16(pa[mt], vb, acc_o[mt][ntv], 0, 0, 0);
            }
        }
    }

    #pragma unroll
    for (int mt = 0; mt < 2; ++mt) {
        #pragma unroll
        for (int r = 0; r < 4; ++r) {
            float inv = 1.f / lrow[mt][r];
            int q_idx = qbase + wid * 32 + mt * 16 + qd * 4 + r;
            float* orow = outp + ((size_t)bh * SL + q_idx) * DK;
            #pragma unroll
            for (int ntv = 0; ntv < 4; ++ntv)
                orow[ntv * 16 + ln] = acc_o[mt][ntv][r] * inv;
        }
    }
}

// ---------------- kernel 6: final loss ----------------
__global__ void k_final(const float* __restrict__ acc_g, float* __restrict__ outp) {
    outp[8388608] = -(acc_g[0] * (1.f / (float)NROWS)) + acc_g[1];
}

extern "C" void kernel_launch(void* const* d_in, const int* in_sizes, int n_in,
                              void* d_out, int out_size, void* d_ws, size_t ws_size,
                              hipStream_t stream) {
    const float* Q   = (const float*)d_in[0];
    const float* K   = (const float*)d_in[1];
    const float* V   = (const float*)d_in[2];
    const float* Wq1 = (const float*)d_in[7];
    const float* bq1 = (const float*)d_in[8];
    const float* Wq2 = (const float*)d_in[9];
    const float* bq2 = (const float*)d_in[10];
    const float* Wp  = (const float*)d_in[11];
    const float* bp  = (const float*)d_in[12];
    float* out = (float*)d_out;

    float* ws      = (float*)d_ws;
    float* Kp      = ws;                 // 933888
    float* Vp      = ws + 933888;        // 933888
    float* mu      = ws + 1867776;       // 182400
    float* centers = ws + 2050176;       // 182400
    float* ccs     = ws + 2232576;       // 933888
    float* acc     = ws + 3166464;       // 4
    bf16_t* W1T    = (bf16_t*)(ws + 3166468);  // 48*512 bf16 = 49152 B

    k_init<<<1, 64, 0, stream>>>(acc);
    k_prep<<<96, 256, 0, stream>>>(Wq1, W1T);
    k_pool<<<(2 * KP_TOT + 255) / 256, 256, 0, stream>>>(K, V, Kp, Vp);
    k_mlp<<<NB * LK, 256, 0, stream>>>(Kp, W1T, bq1, Wq2, bq2, mu, centers, acc);
    k_ce<<<NB * 100, 64, 0, stream>>>(mu, acc);
    k_ccs<<<(KP_TOT + 255) / 256, 256, 0, stream>>>(centers, Wp, bp, ccs);
    k_attn<<<NB * NH * (SL / QT), 256, 0, stream>>>(Q, ccs, Vp, out);
    k_final<<<1, 1, 0, stream>>>(acc, out);
}

// Round 6
// 364.269 us; speedup vs baseline: 1.2636x; 1.2297x over previous
//
#include <hip/hip_runtime.h>
#include <math.h>

#define NCL 10
#define DM 512
#define NH 8
#define DK 64
#define NB 8
#define SL 2048
#define LK 228
#define UF 100
#define KP_PER_B (NH*LK*DK)     // 116736
#define KP_TOT (NB*KP_PER_B)    // 933888
#define NROWS (NB*LK*UF)        // 182400

typedef __bf16 bf16_t;
typedef __attribute__((ext_vector_type(2))) __bf16 bf16x2;
typedef __attribute__((ext_vector_type(4))) __bf16 bf16x4;
typedef __attribute__((ext_vector_type(8))) __bf16 bf16x8;
typedef __attribute__((ext_vector_type(4))) float f32x4;

__device__ __forceinline__ float gelu_f(float x) {
    return 0.5f * x * (1.f + erff(x * 0.70710678118654752f));
}

// ---------------- kernel 0: zero accumulators ----------------
__global__ void k_init(float* __restrict__ acc) {
    if (threadIdx.x < 4) acc[threadIdx.x] = 0.f;
}

// ---------------- kernel 0b: Wq1 -> bf16 flat [512][40] ----------------
__global__ void k_prep(const float* __restrict__ Wq1, bf16_t* __restrict__ W1b) {
    int i = blockIdx.x * 256 + threadIdx.x;
    if (i < 512 * 40) W1b[i] = (bf16_t)Wq1[i];
}

// ---------------- kernel 1: max-pool K and V ----------------
__global__ void k_pool(const float* __restrict__ K, const float* __restrict__ V,
                       float* __restrict__ Kp, float* __restrict__ Vp) {
    int idx = blockIdx.x * 256 + threadIdx.x;
    if (idx >= 2 * KP_TOT) return;
    const float* src = (idx < KP_TOT) ? K : V;
    float* dst = (idx < KP_TOT) ? Kp : Vp;
    int e = (idx < KP_TOT) ? idx : idx - KP_TOT;
    int b   = e / KP_PER_B;
    int off = e % KP_PER_B;
    int c  = off / LK;        // channel 0..511
    int pp = off % LK;        // pooled position 0..227
    int p0 = pp * 9 - 4;
    const float* base = src + (size_t)b * 1048576 + (size_t)c * 2048;
    float mx = -3.4e38f;
    #pragma unroll
    for (int j = 0; j < 9; ++j) {
        int p = p0 + j;
        if (p >= 0 && p < 2048) mx = fmaxf(mx, base[p]);
    }
    dst[e] = mx;
}

// ---------------- kernel 2: sparse q-MLP, virtual-thread quad formulation ----
// Row m of X (100x512 per (b,l)) has nonzeros at g = 512m..512m+511 with
// g mod 100 = 99-b+s (s=1..b), value Sst[s][r] where g = 100r + (99-b+s).
// Virtual thread vt=(m,n4) owns output quad h[m][4*n4..4*n4+3]: for each s
// (uniform trip b), enumerate the 5-6 g's directly; per term one LDS
// broadcast + one 8B W1 chunk (10 threads/m coalesce) + 4 FMA. No atomics,
// no barriers in the loop, fixed layout. W1 bf16 40KB -> L1-resident.
// LDS: Sst2 bf16[8][512] @0 (8192) | hT f32[100][41] @8192 (16400) |
//      stats f32[111] @24592
__global__ __launch_bounds__(256, 6) void k_mlp(
        const float* __restrict__ Kp, const bf16_t* __restrict__ W1b,
        const float* __restrict__ bq1,
        const float* __restrict__ Wq2, const float* __restrict__ bq2,
        float* __restrict__ mu_g, float* __restrict__ centers_g,
        float* __restrict__ acc_g) {
    __shared__ __align__(16) char smem[25040];
    bf16_t* Sst2  = (bf16_t*)smem;               // [8][512], rows 1..7 used
    float*  hT    = (float*)(smem + 8192);       // [100][41]
    float*  stats = (float*)(smem + 24592);      // [0..9]=total [10..109]=S [110]=lp

    int tid = threadIdx.x;
    int bl = blockIdx.x;          // 0..1823
    int b = bl / LK;
    int l = bl % LK;

    // stage Sst2 rows 1..b: coalesced contiguous copy from Kp (b==0: nothing)
    for (int s = tid; s < 512 * b; s += 256) {
        int bk = (s >> 9) + 1;
        int rl = s & 511;
        Sst2[(bk << 9) + rl] = (bf16_t)Kp[bk * KP_PER_B + l * 512 + rl];
    }
    if (tid < 111) stats[tid] = 0.f;
    __syncthreads();

    // layer 1: 1000 virtual threads (m 0..99, n4 0..9), 4 per real thread
    #pragma unroll
    for (int k = 0; k < 4; ++k) {
        int vt = tid + (k << 8);
        if (vt < 1000) {
            int m = vt / 10;
            int n4 = vt - m * 10;
            int base = m << 9;
            float4 h4 = make_float4(0.f, 0.f, 0.f, 0.f);
            for (int s = 1; s <= b; ++s) {
                int t = 99 - b + s;
                int d = (t + 51200 - base) % 100;
                int g = base + d;
                int r = (g - t) / 100;
                const bf16_t* srow = &Sst2[s << 9];
                #pragma unroll 1
                for (; g < base + 512; g += 100, ++r) {
                    float v = (float)srow[r];
                    bf16x4 w = *(const bf16x4*)&W1b[(g - base) * 40 + n4 * 4];
                    h4.x = fmaf(v, (float)w[0], h4.x);
                    h4.y = fmaf(v, (float)w[1], h4.y);
                    h4.z = fmaf(v, (float)w[2], h4.z);
                    h4.w = fmaf(v, (float)w[3], h4.w);
                }
            }
            float* hrow = &hT[m * 41 + n4 * 4];
            hrow[0] = h4.x;
            hrow[1] = h4.y;
            hrow[2] = h4.z;
            hrow[3] = h4.w;
        }
    }
    __syncthreads();

    // gelu(+bias) in place, distributed
    for (int i = tid; i < 4000; i += 256) {
        int row = i / 40;
        int j = i - row * 40;
        hT[row * 41 + j] = gelu_f(hT[row * 41 + j] + bq1[j]);
    }
    __syncthreads();

    float* total_l = stats;
    float* S_l = stats + 10;
    float* lp_acc = stats + 110;

    if (tid < 100) {
        int row = tid;
        float out[10];
        #pragma unroll
        for (int c = 0; c < 10; ++c) out[c] = bq2[c];
        #pragma unroll
        for (int j = 0; j < 40; ++j) {
            float gj = hT[row * 41 + j];
            #pragma unroll
            for (int c = 0; c < 10; ++c)
                out[c] = fmaf(gj, Wq2[j * 10 + c], out[c]);
        }
        float m = out[0]; int am = 0;
        #pragma unroll
        for (int c = 1; c < 10; ++c)
            if (out[c] > m) { m = out[c]; am = c; }
        float e[10], s = 0.f;
        #pragma unroll
        for (int c = 0; c < 10; ++c) { e[c] = expf(out[c] - m); s += e[c]; }
        float inv = 1.f / s;
        float cq[10], s1 = 0.f;
        #pragma unroll
        for (int c = 0; c < 10; ++c) { cq[c] = e[c] * inv; s1 += cq[c]; }
        float mean = s1 * 0.1f;
        float var = 0.f;
        #pragma unroll
        for (int c = 0; c < 10; ++c) { float d = cq[c] - mean; var += d * d; }
        float sd = sqrtf(var / 9.f);
        float sp = log1pf(expf(sd));             // softplus(std)
        float lp = -logf(sp) - 0.91893853320467274f;  // ((x-mu)/sigma)^2 ~ 1e-16
        mu_g[bl * 100 + row] = mean;
        atomicAdd(lp_acc, lp);
        #pragma unroll
        for (int c = 0; c < 10; ++c) {
            atomicAdd(&total_l[c], cq[c]);
            atomicAdd(&S_l[am * 10 + c], cq[c]);
        }
    }
    __syncthreads();
    if (tid == 0) atomicAdd(&acc_g[0], lp_acc[0]);
    if (tid < 100) {
        centers_g[bl * 100 + tid] = (total_l[tid % 10] - S_l[tid]) * 0.01f;
    }
}

// ---------------- kernel 3: cross-entropy over l axis ----------------
__global__ void k_ce(const float* __restrict__ mu_g, float* __restrict__ acc_g) {
    int bid = blockIdx.x;     // 800 = (b,u)
    int b = bid / 100;
    int u = bid % 100;
    int lane = threadIdx.x;   // 64
    float v[4];
    #pragma unroll
    for (int t = 0; t < 4; ++t) {
        int l = lane + t * 64;
        v[t] = (l < LK) ? mu_g[(b * LK + l) * 100 + u] : -3.4e38f;
    }
    float m = fmaxf(fmaxf(v[0], v[1]), fmaxf(v[2], v[3]));
    for (int o = 32; o > 0; o >>= 1) m = fmaxf(m, __shfl_xor(m, o, 64));
    float se = 0.f;
    #pragma unroll
    for (int t = 0; t < 4; ++t) {
        int l = lane + t * 64;
        if (l < LK) se += expf(v[t] - m);
    }
    for (int o = 32; o > 0; o >>= 1) se += __shfl_xor(se, o, 64);
    float lse = m + logf(se);
    float dot = 0.f;
    #pragma unroll
    for (int t = 0; t < 4; ++t) {
        int l = lane + t * 64;
        if (l < LK) dot += v[t] * (v[t] - lse);
    }
    for (int o = 32; o > 0; o >>= 1) dot += __shfl_xor(dot, o, 64);
    if (lane == 0) atomicAdd(&acc_g[1], -dot * (1.f / 800.f));
}

// ---------------- kernel 4: fused proj_back(gelu) + reshape-sum over clusters ----------------
__global__ void k_ccs(const float* __restrict__ centers_g,
                      const float* __restrict__ Wp, const float* __restrict__ bp,
                      float* __restrict__ ccs) {
    int tid = blockIdx.x * 256 + threadIdx.x;
    if (tid >= KP_TOT) return;
    int k2d2 = tid % (LK * DK);
    int bh = tid / (LK * DK);
    float s = 0.f;
    #pragma unroll
    for (int i2 = 0; i2 < 10; ++i2) {
        int t2 = bh * 145920 + i2 * 14592 + k2d2;   // flat index into cc [10,8,228,512]
        int i = t2 / 933888;
        int r1 = t2 % 933888;
        int bs = r1 / 116736;
        int r2 = r1 % 116736;
        int ls = r2 / 512;
        int mm = r2 % 512;
        const float* cen = centers_g + (bs * LK + ls) * 100 + i * 10;
        float val = bp[mm];
        #pragma unroll
        for (int c = 0; c < 10; ++c)
            val = fmaf(cen[c], Wp[c * 512 + mm], val);
        s += gelu_f(val);
    }
    ccs[tid] = s;
}

// ---------------- kernel 5: MFMA flash attention (228 keys, chunks of 64) ----------------
#define QT 128
__global__ __launch_bounds__(256, 3) void k_attn(
        const float* __restrict__ Q, const float* __restrict__ ccs,
        const float* __restrict__ Vp, float* __restrict__ outp) {
    __shared__ __align__(16) char smem[36864];
    bf16_t* Kl = (bf16_t*)(smem);
    bf16_t* Vt = (bf16_t*)(smem + 9216);
    bf16_t* Pl = (bf16_t*)(smem + 18432);

    int tid = threadIdx.x;
    int wid = tid >> 6;
    int lane = tid & 63;
    int ln = lane & 15;
    int qd = lane >> 4;
    int bid = blockIdx.x;        // 1024
    int bh = bid >> 4;           // b*8+h
    int qt = bid & 15;
    int qbase = qt * QT;

    const float* Qbh = Q + (size_t)bh * SL * DK;
    const float* Kbh = ccs + (size_t)bh * LK * DK;
    const float* Vbh = Vp + (size_t)bh * LK * DK;

    for (int s = tid; s < QT * 32; s += 256) {
        int r = s >> 5;
        int c2 = s & 31;
        float2 v = *(const float2*)&Qbh[(size_t)(qbase + r) * DK + c2 * 2];
        *(bf16x2*)&Pl[r * 72 + c2 * 2] = (bf16x2){(bf16_t)v.x, (bf16_t)v.y};
    }
    __syncthreads();
    bf16x8 qf[2][2];
    #pragma unroll
    for (int mt = 0; mt < 2; ++mt)
        #pragma unroll
        for (int ks = 0; ks < 2; ++ks)
            qf[mt][ks] = *(const bf16x8*)&Pl[(wid * 32 + mt * 16 + ln) * 72 + ks * 32 + qd * 8];

    f32x4 acc_o[2][4];
    float mrow[2][4], lrow[2][4];
    #pragma unroll
    for (int mt = 0; mt < 2; ++mt)
        #pragma unroll
        for (int t = 0; t < 4; ++t) {
            acc_o[mt][t] = (f32x4)(0.f);
            mrow[mt][t] = -3.0e38f;
            lrow[mt][t] = 0.f;
        }

    for (int ch = 0; ch < 4; ++ch) {
        int k0 = ch * 64;
        __syncthreads();
        for (int s = tid; s < 64 * 32; s += 256) {
            int kk = s >> 5;
            int c2 = s & 31;
            int key = k0 + kk;
            float2 v = (key < LK) ? *(const float2*)&Kbh[(size_t)key * DK + c2 * 2]
                                  : make_float2(0.f, 0.f);
            *(bf16x2*)&Kl[kk * 72 + c2 * 2] = (bf16x2){(bf16_t)v.x, (bf16_t)v.y};
        }
        for (int s = tid; s < 64 * 16; s += 256) {
            int kk = s >> 4;
            int c4 = s & 15;
            int key = k0 + kk;
            float4 v = (key < LK) ? *(const float4*)&Vbh[(size_t)key * DK + c4 * 4]
                                  : make_float4(0.f, 0.f, 0.f, 0.f);
            Vt[(c4 * 4 + 0) * 72 + kk] = (bf16_t)v.x;
            Vt[(c4 * 4 + 1) * 72 + kk] = (bf16_t)v.y;
            Vt[(c4 * 4 + 2) * 72 + kk] = (bf16_t)v.z;
            Vt[(c4 * 4 + 3) * 72 + kk] = (bf16_t)v.w;
        }
        __syncthreads();

        f32x4 accs[2][4];
        #pragma unroll
        for (int mt = 0; mt < 2; ++mt)
            #pragma unroll
            for (int nt = 0; nt < 4; ++nt) accs[mt][nt] = (f32x4)(0.f);
        #pragma unroll
        for (int ks = 0; ks < 2; ++ks) {
            #pragma unroll
            for (int nt = 0; nt < 4; ++nt) {
                bf16x8 bf = *(const bf16x8*)&Kl[(nt * 16 + ln) * 72 + ks * 32 + qd * 8];
                #pragma unroll
                for (int mt = 0; mt < 2; ++mt)
                    accs[mt][nt] = __builtin_amdgcn_mfma_f32_16x16x32_bf16(qf[mt][ks], bf, accs[mt][nt], 0, 0, 0);
            }
        }

        #pragma unroll
        for (int mt = 0; mt < 2; ++mt) {
            #pragma unroll
            for (int r = 0; r < 4; ++r) {
                float sv[4];
                #pragma unroll
                for (int nt = 0; nt < 4; ++nt) {
                    float s = accs[mt][nt][r] * 0.125f;
                    int key = k0 + nt * 16 + ln;
                    sv[nt] = (key < LK) ? s : -3.0e38f;
                }
                float rmax = fmaxf(fmaxf(sv[0], sv[1]), fmaxf(sv[2], sv[3]));
                #pragma unroll
                for (int o = 1; o < 16; o <<= 1)
                    rmax = fmaxf(rmax, __shfl_xor(rmax, o, 64));
                float mold = mrow[mt][r];
                float mnew = fmaxf(mold, rmax);
                float alpha = __expf(mold - mnew);
                float p[4], psum = 0.f;
                #pragma unroll
                for (int nt = 0; nt < 4; ++nt) {
                    p[nt] = __expf(sv[nt] - mnew);
                    psum += p[nt];
                }
                #pragma unroll
                for (int o = 1; o < 16; o <<= 1)
                    psum += __shfl_xor(psum, o, 64);
                lrow[mt][r] = lrow[mt][r] * alpha + psum;
                mrow[mt][r] = mnew;
                #pragma unroll
                for (int ntv = 0; ntv < 4; ++ntv)
                    acc_o[mt][ntv][r] *= alpha;
                int prow = (wid * 32 + mt * 16 + qd * 4 + r) * 72;
                #pragma unroll
                for (int nt = 0; nt < 4; ++nt)
                    Pl[prow + nt * 16 + ln] = (bf16_t)p[nt];
            }
        }

        #pragma unroll
        for (int ks = 0; ks < 2; ++ks) {
            bf16x8 pa[2];
            #pragma unroll
            for (int mt = 0; mt < 2; ++mt)
                pa[mt] = *(const bf16x8*)&Pl[(wid * 32 + mt * 16 + ln) * 72 + ks * 32 + qd * 8];
            #pragma unroll
            for (int ntv = 0; ntv < 4; ++ntv) {
                bf16x8 vb = *(const bf16x8*)&Vt[(ntv * 16 + ln) * 72 + ks * 32 + qd * 8];
                #pragma unroll
                for (int mt = 0; mt < 2; ++mt)
                    acc_o[mt][ntv] = __builtin_amdgcn_mfma_f32_16x16x32_bf16(pa[mt], vb, acc_o[mt][ntv], 0, 0, 0);
            }
        }
    }

    #pragma unroll
    for (int mt = 0; mt < 2; ++mt) {
        #pragma unroll
        for (int r = 0; r < 4; ++r) {
            float inv = 1.f / lrow[mt][r];
            int q_idx = qbase + wid * 32 + mt * 16 + qd * 4 + r;
            float* orow = outp + ((size_t)bh * SL + q_idx) * DK;
            #pragma unroll
            for (int ntv = 0; ntv < 4; ++ntv)
                orow[ntv * 16 + ln] = acc_o[mt][ntv][r] * inv;
        }
    }
}

// ---------------- kernel 6: final loss ----------------
__global__ void k_final(const float* __restrict__ acc_g, float* __restrict__ outp) {
    outp[8388608] = -(acc_g[0] * (1.f / (float)NROWS)) + acc_g[1];
}

extern "C" void kernel_launch(void* const* d_in, const int* in_sizes, int n_in,
                              void* d_out, int out_size, void* d_ws, size_t ws_size,
                              hipStream_t stream) {
    const float* Q   = (const float*)d_in[0];
    const float* K   = (const float*)d_in[1];
    const float* V   = (const float*)d_in[2];
    const float* Wq1 = (const float*)d_in[7];
    const float* bq1 = (const float*)d_in[8];
    const float* Wq2 = (const float*)d_in[9];
    const float* bq2 = (const float*)d_in[10];
    const float* Wp  = (const float*)d_in[11];
    const float* bp  = (const float*)d_in[12];
    float* out = (float*)d_out;

    float* ws      = (float*)d_ws;
    float* Kp      = ws;                 // 933888
    float* Vp      = ws + 933888;        // 933888
    float* mu      = ws + 1867776;       // 182400
    float* centers = ws + 2050176;       // 182400
    float* ccs     = ws + 2232576;       // 933888
    float* acc     = ws + 3166464;       // 4
    bf16_t* W1b    = (bf16_t*)(ws + 3166468);  // 512*40 bf16 = 40960 B

    k_init<<<1, 64, 0, stream>>>(acc);
    k_prep<<<80, 256, 0, stream>>>(Wq1, W1b);
    k_pool<<<(2 * KP_TOT + 255) / 256, 256, 0, stream>>>(K, V, Kp, Vp);
    k_mlp<<<NB * LK, 256, 0, stream>>>(Kp, W1b, bq1, Wq2, bq2, mu, centers, acc);
    k_ce<<<NB * 100, 64, 0, stream>>>(mu, acc);
    k_ccs<<<(KP_TOT + 255) / 256, 256, 0, stream>>>(centers, Wp, bp, ccs);
    k_attn<<<NB * NH * (SL / QT), 256, 0, stream>>>(Q, ccs, Vp, out);
    k_final<<<1, 1, 0, stream>>>(acc, out);
}

// Round 7
// 348.323 us; speedup vs baseline: 1.3214x; 1.0458x over previous
//
#include <hip/hip_runtime.h>
#include <math.h>

#define NCL 10
#define DM 512
#define NH 8
#define DK 64
#define NB 8
#define SL 2048
#define LK 228
#define UF 100
#define KP_PER_B (NH*LK*DK)     // 116736
#define KP_TOT (NB*KP_PER_B)    // 933888
#define NROWS (NB*LK*UF)        // 182400
#define POOL_BLOCKS 7296        // 2*KP_TOT/256

typedef __bf16 bf16_t;
typedef __attribute__((ext_vector_type(2))) __bf16 bf16x2;
typedef __attribute__((ext_vector_type(8))) __bf16 bf16x8;
typedef __attribute__((ext_vector_type(4))) float f32x4;

__device__ __forceinline__ float gelu_f(float x) {
    return 0.5f * x * (1.f + erff(x * 0.70710678118654752f));
}

// ------------- kernel 1: max-pool K,V  (+ fused: W1->bf16 prep, acc init) ----
__global__ void k_pool(const float* __restrict__ K, const float* __restrict__ V,
                       float* __restrict__ Kp, float* __restrict__ Vp,
                       const float* __restrict__ Wq1, bf16_t* __restrict__ W1b,
                       float* __restrict__ acc) {
    int bid = blockIdx.x;
    if (bid >= POOL_BLOCKS) {
        int i = (bid - POOL_BLOCKS) * 256 + threadIdx.x;
        if (i < 512 * 40) W1b[i] = (bf16_t)Wq1[i];
        if (bid == POOL_BLOCKS && threadIdx.x < 4) acc[threadIdx.x] = 0.f;
        return;
    }
    int idx = bid * 256 + threadIdx.x;
    const float* src = (idx < KP_TOT) ? K : V;
    float* dst = (idx < KP_TOT) ? Kp : Vp;
    int e = (idx < KP_TOT) ? idx : idx - KP_TOT;
    int b   = e / KP_PER_B;
    int off = e % KP_PER_B;
    int c  = off / LK;        // channel 0..511
    int pp = off % LK;        // pooled position 0..227
    int p0 = pp * 9 - 4;
    const float* base = src + (size_t)b * 1048576 + (size_t)c * 2048;
    float mx = -3.4e38f;
    #pragma unroll
    for (int j = 0; j < 9; ++j) {
        int p = p0 + j;
        if (p >= 0 && p < 2048) mx = fmaxf(mx, base[p]);
    }
    dst[e] = mx;
}

// ------------- kernel 2: sparse q-MLP, b-specialized unrolled layer 1 --------
// X row m (of 100x512 per (b,l)) nonzeros: g=512m+c with g%100 = t(s)=99-B+s,
// s=1..B, value Sstf[s][r], r=(g-t)/100. Per (m,s): d0=(t-12m)%100, terms at
// c = d0+100j (5 always, 6th iff d0<12), r = r0+j. Full compile-time unroll
// gives ~42 independent loads per virtual thread (ILP covers L2 latency).
// vt=(m,h8): 8 hidden cols per thread, bf16x8 W1 load (5 lanes coalesce 80B).
// LDS: Sstf f32[8][512] @0 (16384) | hT f32[100][44] @16384 (17600) |
//      stats f32[111] @33984 -> 34428 B, 4 blocks/CU.
template<int B>
__device__ __forceinline__ void layer1(int tid, const bf16_t* __restrict__ W1b,
                                       const float* __restrict__ Sstf,
                                       float* __restrict__ hT) {
    #pragma unroll 1
    for (int k = 0; k < 2; ++k) {
        int vt = tid + (k << 8);
        if (vt < 500) {
            int m = vt / 5;
            int h8 = vt - m * 5;            // 0..4 -> cols h8*8..h8*8+7
            int bm = (12 * m) % 100;
            float h[8];
            #pragma unroll
            for (int i = 0; i < 8; ++i) h[i] = 0.f;
            #pragma unroll
            for (int s = 1; s <= B; ++s) {
                const int t = 99 - B + s;
                int d0 = t - bm; if (d0 < 0) d0 += 100;
                int r0 = ((m << 9) + d0 - t) / 100;   // exact division
                const float* srow = &Sstf[s << 9];
                #pragma unroll
                for (int j = 0; j < 6; ++j) {
                    int c = d0 + j * 100;
                    if (j < 5 || c < 512) {
                        float v = srow[r0 + j];
                        bf16x8 w = *(const bf16x8*)&W1b[c * 40 + h8 * 8];
                        #pragma unroll
                        for (int i = 0; i < 8; ++i)
                            h[i] = fmaf(v, (float)w[i], h[i]);
                    }
                }
            }
            #pragma unroll
            for (int i = 0; i < 8; ++i) hT[m * 44 + h8 * 8 + i] = h[i];
        }
    }
}

__global__ __launch_bounds__(256, 4) void k_mlp(
        const float* __restrict__ Kp, const bf16_t* __restrict__ W1b,
        const float* __restrict__ bq1,
        const float* __restrict__ Wq2, const float* __restrict__ bq2,
        float* __restrict__ mu_g, float* __restrict__ centers_g,
        float* __restrict__ acc_g) {
    __shared__ __align__(16) char smem[34432];
    float* Sstf  = (float*)smem;                 // [8][512], rows 1..7 used
    float* hT    = (float*)(smem + 16384);       // [100][44]
    float* stats = (float*)(smem + 33984);       // [0..9]=total [10..109]=S [110]=lp

    int tid = threadIdx.x;
    int bl = blockIdx.x;          // 0..1823
    int b = bl / LK;
    int l = bl % LK;

    // stage Sstf rows 1..b: coalesced float4 copy from Kp
    for (int s4 = tid; s4 < 128 * b; s4 += 256) {
        int bk = (s4 >> 7) + 1;
        int r4 = (s4 & 127) << 2;
        *(float4*)&Sstf[(bk << 9) + r4] =
            *(const float4*)&Kp[bk * KP_PER_B + l * 512 + r4];
    }
    if (tid < 111) stats[tid] = 0.f;
    if (b == 0) {
        for (int i = tid; i < 4400; i += 256) hT[i] = 0.f;
    }
    __syncthreads();

    switch (b) {
        case 1: layer1<1>(tid, W1b, Sstf, hT); break;
        case 2: layer1<2>(tid, W1b, Sstf, hT); break;
        case 3: layer1<3>(tid, W1b, Sstf, hT); break;
        case 4: layer1<4>(tid, W1b, Sstf, hT); break;
        case 5: layer1<5>(tid, W1b, Sstf, hT); break;
        case 6: layer1<6>(tid, W1b, Sstf, hT); break;
        case 7: layer1<7>(tid, W1b, Sstf, hT); break;
        default: break;
    }
    __syncthreads();

    // gelu(+bias) in place, distributed
    for (int i = tid; i < 4000; i += 256) {
        int row = i / 40;
        int j = i - row * 40;
        hT[row * 44 + j] = gelu_f(hT[row * 44 + j] + bq1[j]);
    }
    __syncthreads();

    float* total_l = stats;
    float* S_l = stats + 10;
    float* lp_acc = stats + 110;

    if (tid < 100) {
        int row = tid;
        float g[40];
        #pragma unroll
        for (int j4 = 0; j4 < 10; ++j4) {
            float4 gv = *(const float4*)&hT[row * 44 + j4 * 4];
            g[j4 * 4 + 0] = gv.x; g[j4 * 4 + 1] = gv.y;
            g[j4 * 4 + 2] = gv.z; g[j4 * 4 + 3] = gv.w;
        }
        float out[10];
        #pragma unroll
        for (int c = 0; c < 10; ++c) out[c] = bq2[c];
        #pragma unroll
        for (int j = 0; j < 40; ++j) {
            float gj = g[j];
            #pragma unroll
            for (int c = 0; c < 10; ++c)
                out[c] = fmaf(gj, Wq2[j * 10 + c], out[c]);
        }
        float m = out[0]; int am = 0;
        #pragma unroll
        for (int c = 1; c < 10; ++c)
            if (out[c] > m) { m = out[c]; am = c; }
        float e[10], s = 0.f;
        #pragma unroll
        for (int c = 0; c < 10; ++c) { e[c] = expf(out[c] - m); s += e[c]; }
        float inv = 1.f / s;
        float cq[10], s1 = 0.f;
        #pragma unroll
        for (int c = 0; c < 10; ++c) { cq[c] = e[c] * inv; s1 += cq[c]; }
        float mean = s1 * 0.1f;
        float var = 0.f;
        #pragma unroll
        for (int c = 0; c < 10; ++c) { float d = cq[c] - mean; var += d * d; }
        float sd = sqrtf(var / 9.f);
        float sp = log1pf(expf(sd));             // softplus(std)
        float lp = -logf(sp) - 0.91893853320467274f;  // ((x-mu)/sigma)^2 ~ 1e-16
        mu_g[bl * 100 + row] = mean;
        atomicAdd(lp_acc, lp);
        #pragma unroll
        for (int c = 0; c < 10; ++c) {
            atomicAdd(&total_l[c], cq[c]);
            atomicAdd(&S_l[am * 10 + c], cq[c]);
        }
    }
    __syncthreads();
    if (tid == 0) atomicAdd(&acc_g[0], lp_acc[0]);
    if (tid < 100) {
        centers_g[bl * 100 + tid] = (total_l[tid % 10] - S_l[tid]) * 0.01f;
    }
}

// ------------- kernel 3: cross-entropy over l axis (+ fused final loss) -----
__global__ void k_ce(const float* __restrict__ mu_g, float* __restrict__ acc_g,
                     float* __restrict__ outp) {
    int bid = blockIdx.x;     // 800 = (b,u)
    int b = bid / 100;
    int u = bid % 100;
    int lane = threadIdx.x;   // 64
    float v[4];
    #pragma unroll
    for (int t = 0; t < 4; ++t) {
        int l = lane + t * 64;
        v[t] = (l < LK) ? mu_g[(b * LK + l) * 100 + u] : -3.4e38f;
    }
    float m = fmaxf(fmaxf(v[0], v[1]), fmaxf(v[2], v[3]));
    for (int o = 32; o > 0; o >>= 1) m = fmaxf(m, __shfl_xor(m, o, 64));
    float se = 0.f;
    #pragma unroll
    for (int t = 0; t < 4; ++t) {
        int l = lane + t * 64;
        if (l < LK) se += expf(v[t] - m);
    }
    for (int o = 32; o > 0; o >>= 1) se += __shfl_xor(se, o, 64);
    float lse = m + logf(se);
    float dot = 0.f;
    #pragma unroll
    for (int t = 0; t < 4; ++t) {
        int l = lane + t * 64;
        if (l < LK) dot += v[t] * (v[t] - lse);
    }
    for (int o = 32; o > 0; o >>= 1) dot += __shfl_xor(dot, o, 64);
    if (lane == 0) {
        atomicAdd(&acc_g[1], -dot * (1.f / 800.f));
        __threadfence();
        unsigned int old = atomicAdd((unsigned int*)&acc_g[2], 1u);
        if (old == 799u) {
            __threadfence();
            outp[8388608] = -(acc_g[0] * (1.f / (float)NROWS)) + acc_g[1];
        }
    }
}

// ------------- kernel 4: fused proj_back(gelu) + reshape-sum over clusters --
__global__ void k_ccs(const float* __restrict__ centers_g,
                      const float* __restrict__ Wp, const float* __restrict__ bp,
                      float* __restrict__ ccs) {
    int tid = blockIdx.x * 256 + threadIdx.x;
    if (tid >= KP_TOT) return;
    int k2d2 = tid % (LK * DK);
    int bh = tid / (LK * DK);
    float s = 0.f;
    #pragma unroll
    for (int i2 = 0; i2 < 10; ++i2) {
        int t2 = bh * 145920 + i2 * 14592 + k2d2;   // flat index into cc [10,8,228,512]
        int i = t2 / 933888;
        int r1 = t2 % 933888;
        int bs = r1 / 116736;
        int r2 = r1 % 116736;
        int ls = r2 / 512;
        int mm = r2 % 512;
        const float* cen = centers_g + (bs * LK + ls) * 100 + i * 10;
        float val = bp[mm];
        #pragma unroll
        for (int c = 0; c < 10; ++c)
            val = fmaf(cen[c], Wp[c * 512 + mm], val);
        s += gelu_f(val);
    }
    ccs[tid] = s;
}

// ------------- kernel 5: MFMA flash attention (228 keys, chunks of 64) ------
#define QT 128
__global__ __launch_bounds__(256, 3) void k_attn(
        const float* __restrict__ Q, const float* __restrict__ ccs,
        const float* __restrict__ Vp, float* __restrict__ outp) {
    __shared__ __align__(16) char smem[36864];
    bf16_t* Kl = (bf16_t*)(smem);
    bf16_t* Vt = (bf16_t*)(smem + 9216);
    bf16_t* Pl = (bf16_t*)(smem + 18432);

    int tid = threadIdx.x;
    int wid = tid >> 6;
    int lane = tid & 63;
    int ln = lane & 15;
    int qd = lane >> 4;
    int bid = blockIdx.x;        // 1024
    int bh = bid >> 4;           // b*8+h
    int qt = bid & 15;
    int qbase = qt * QT;

    const float* Qbh = Q + (size_t)bh * SL * DK;
    const float* Kbh = ccs + (size_t)bh * LK * DK;
    const float* Vbh = Vp + (size_t)bh * LK * DK;

    for (int s = tid; s < QT * 32; s += 256) {
        int r = s >> 5;
        int c2 = s & 31;
        float2 v = *(const float2*)&Qbh[(size_t)(qbase + r) * DK + c2 * 2];
        *(bf16x2*)&Pl[r * 72 + c2 * 2] = (bf16x2){(bf16_t)v.x, (bf16_t)v.y};
    }
    __syncthreads();
    bf16x8 qf[2][2];
    #pragma unroll
    for (int mt = 0; mt < 2; ++mt)
        #pragma unroll
        for (int ks = 0; ks < 2; ++ks)
            qf[mt][ks] = *(const bf16x8*)&Pl[(wid * 32 + mt * 16 + ln) * 72 + ks * 32 + qd * 8];

    f32x4 acc_o[2][4];
    float mrow[2][4], lrow[2][4];
    #pragma unroll
    for (int mt = 0; mt < 2; ++mt)
        #pragma unroll
        for (int t = 0; t < 4; ++t) {
            acc_o[mt][t] = (f32x4)(0.f);
            mrow[mt][t] = -3.0e38f;
            lrow[mt][t] = 0.f;
        }

    for (int ch = 0; ch < 4; ++ch) {
        int k0 = ch * 64;
        __syncthreads();
        for (int s = tid; s < 64 * 32; s += 256) {
            int kk = s >> 5;
            int c2 = s & 31;
            int key = k0 + kk;
            float2 v = (key < LK) ? *(const float2*)&Kbh[(size_t)key * DK + c2 * 2]
                                  : make_float2(0.f, 0.f);
            *(bf16x2*)&Kl[kk * 72 + c2 * 2] = (bf16x2){(bf16_t)v.x, (bf16_t)v.y};
        }
        for (int s = tid; s < 64 * 16; s += 256) {
            int kk = s >> 4;
            int c4 = s & 15;
            int key = k0 + kk;
            float4 v = (key < LK) ? *(const float4*)&Vbh[(size_t)key * DK + c4 * 4]
                                  : make_float4(0.f, 0.f, 0.f, 0.f);
            Vt[(c4 * 4 + 0) * 72 + kk] = (bf16_t)v.x;
            Vt[(c4 * 4 + 1) * 72 + kk] = (bf16_t)v.y;
            Vt[(c4 * 4 + 2) * 72 + kk] = (bf16_t)v.z;
            Vt[(c4 * 4 + 3) * 72 + kk] = (bf16_t)v.w;
        }
        __syncthreads();

        f32x4 accs[2][4];
        #pragma unroll
        for (int mt = 0; mt < 2; ++mt)
            #pragma unroll
            for (int nt = 0; nt < 4; ++nt) accs[mt][nt] = (f32x4)(0.f);
        #pragma unroll
        for (int ks = 0; ks < 2; ++ks) {
            #pragma unroll
            for (int nt = 0; nt < 4; ++nt) {
                bf16x8 bf = *(const bf16x8*)&Kl[(nt * 16 + ln) * 72 + ks * 32 + qd * 8];
                #pragma unroll
                for (int mt = 0; mt < 2; ++mt)
                    accs[mt][nt] = __builtin_amdgcn_mfma_f32_16x16x32_bf16(qf[mt][ks], bf, accs[mt][nt], 0, 0, 0);
            }
        }

        #pragma unroll
        for (int mt = 0; mt < 2; ++mt) {
            #pragma unroll
            for (int r = 0; r < 4; ++r) {
                float sv[4];
                #pragma unroll
                for (int nt = 0; nt < 4; ++nt) {
                    float s = accs[mt][nt][r] * 0.125f;
                    int key = k0 + nt * 16 + ln;
                    sv[nt] = (key < LK) ? s : -3.0e38f;
                }
                float rmax = fmaxf(fmaxf(sv[0], sv[1]), fmaxf(sv[2], sv[3]));
                #pragma unroll
                for (int o = 1; o < 16; o <<= 1)
                    rmax = fmaxf(rmax, __shfl_xor(rmax, o, 64));
                float mold = mrow[mt][r];
                float mnew = fmaxf(mold, rmax);
                float alpha = __expf(mold - mnew);
                float p[4], psum = 0.f;
                #pragma unroll
                for (int nt = 0; nt < 4; ++nt) {
                    p[nt] = __expf(sv[nt] - mnew);
                    psum += p[nt];
                }
                #pragma unroll
                for (int o = 1; o < 16; o <<= 1)
                    psum += __shfl_xor(psum, o, 64);
                lrow[mt][r] = lrow[mt][r] * alpha + psum;
                mrow[mt][r] = mnew;
                #pragma unroll
                for (int ntv = 0; ntv < 4; ++ntv)
                    acc_o[mt][ntv][r] *= alpha;
                int prow = (wid * 32 + mt * 16 + qd * 4 + r) * 72;
                #pragma unroll
                for (int nt = 0; nt < 4; ++nt)
                    Pl[prow + nt * 16 + ln] = (bf16_t)p[nt];
            }
        }

        #pragma unroll
        for (int ks = 0; ks < 2; ++ks) {
            bf16x8 pa[2];
            #pragma unroll
            for (int mt = 0; mt < 2; ++mt)
                pa[mt] = *(const bf16x8*)&Pl[(wid * 32 + mt * 16 + ln) * 72 + ks * 32 + qd * 8];
            #pragma unroll
            for (int ntv = 0; ntv < 4; ++ntv) {
                bf16x8 vb = *(const bf16x8*)&Vt[(ntv * 16 + ln) * 72 + ks * 32 + qd * 8];
                #pragma unroll
                for (int mt = 0; mt < 2; ++mt)
                    acc_o[mt][ntv] = __builtin_amdgcn_mfma_f32_16x16x32_bf16(pa[mt], vb, acc_o[mt][ntv], 0, 0, 0);
            }
        }
    }

    #pragma unroll
    for (int mt = 0; mt < 2; ++mt) {
        #pragma unroll
        for (int r = 0; r < 4; ++r) {
            float inv = 1.f / lrow[mt][r];
            int q_idx = qbase + wid * 32 + mt * 16 + qd * 4 + r;
            float* orow = outp + ((size_t)bh * SL + q_idx) * DK;
            #pragma unroll
            for (int ntv = 0; ntv < 4; ++ntv)
                orow[ntv * 16 + ln] = acc_o[mt][ntv][r] * inv;
        }
    }
}

extern "C" void kernel_launch(void* const* d_in, const int* in_sizes, int n_in,
                              void* d_out, int out_size, void* d_ws, size_t ws_size,
                              hipStream_t stream) {
    const float* Q   = (const float*)d_in[0];
    const float* K   = (const float*)d_in[1];
    const float* V   = (const float*)d_in[2];
    const float* Wq1 = (const float*)d_in[7];
    const float* bq1 = (const float*)d_in[8];
    const float* Wq2 = (const float*)d_in[9];
    const float* bq2 = (const float*)d_in[10];
    const float* Wp  = (const float*)d_in[11];
    const float* bp  = (const float*)d_in[12];
    float* out = (float*)d_out;

    float* ws      = (float*)d_ws;
    float* Kp      = ws;                 // 933888
    float* Vp      = ws + 933888;        // 933888
    float* mu      = ws + 1867776;       // 182400
    float* centers = ws + 2050176;       // 182400
    float* ccs     = ws + 2232576;       // 933888
    float* acc     = ws + 3166464;       // 4 (acc[2] doubles as uint counter)
    bf16_t* W1b    = (bf16_t*)(ws + 3166468);  // 512*40 bf16 = 40960 B

    // pool (+ W1 bf16 prep + acc init) -> mlp -> ccs -> ce(+final) -> attn
    k_pool<<<POOL_BLOCKS + 80, 256, 0, stream>>>(K, V, Kp, Vp, Wq1, W1b, acc);
    k_mlp<<<NB * LK, 256, 0, stream>>>(Kp, W1b, bq1, Wq2, bq2, mu, centers, acc);
    k_ccs<<<(KP_TOT + 255) / 256, 256, 0, stream>>>(centers, Wp, bp, ccs);
    k_ce<<<NB * 100, 64, 0, stream>>>(mu, acc, out);
    k_attn<<<NB * NH * (SL / QT), 256, 0, stream>>>(Q, ccs, Vp, out);
}